// Round 4
// baseline (86.786 us; speedup 1.0000x reference)
//
#include <hip/hip_runtime.h>
#include <hip/hip_bf16.h>

#define B_N 4096
#define E_N 64
#define D_N 1024
#define ROWS 16

typedef __bf16 bf16x8 __attribute__((ext_vector_type(8)));
typedef __bf16 bf16x4 __attribute__((ext_vector_type(4)));
typedef float f32x4 __attribute__((ext_vector_type(4)));

// ws layout (bytes):
// [0, 4096)        sinv   (1024 f32)
// [4096, 4352)     Ak     (64 f32)
// [4352, 135424)   sk_bf16 [64][1024]   (sigma_inv * keys, K-major)
// [135424, 266496) kT_bf16 [1024][64]   (raw keys transposed, K(=e)-major)

__global__ __launch_bounds__(256) void prep_kernel(
    const float* __restrict__ keys, const float* __restrict__ lsig,
    float* __restrict__ sinv, float* __restrict__ ak,
    __bf16* __restrict__ sk, __bf16* __restrict__ kT)
{
  __shared__ float red[4];
  __shared__ __bf16 tl[64][72];          // transpose tile, +8 pad
  const int bid = blockIdx.x;
  const int t = threadIdx.x;

  if (bid < 64) {
    const int e = bid;
    const float4 k4 = *(const float4*)(keys + e * D_N + 4 * t);
    const float4 l4 = *(const float4*)(lsig + 4 * t);
    float4 s4;
    s4.x = expf(-l4.x); s4.y = expf(-l4.y); s4.z = expf(-l4.z); s4.w = expf(-l4.w);
    if (e == 0) *(float4*)(sinv + 4 * t) = s4;
    const float4 sk4 = make_float4(s4.x * k4.x, s4.y * k4.y, s4.z * k4.z, s4.w * k4.w);
    bf16x4 skb;
    skb[0] = (__bf16)sk4.x; skb[1] = (__bf16)sk4.y; skb[2] = (__bf16)sk4.z; skb[3] = (__bf16)sk4.w;
    *(bf16x4*)(sk + e * D_N + 4 * t) = skb;
    float p = sk4.x * k4.x + sk4.y * k4.y + sk4.z * k4.z + sk4.w * k4.w;
    #pragma unroll
    for (int off = 32; off > 0; off >>= 1) p += __shfl_down(p, off);
    if ((t & 63) == 0) red[t >> 6] = p;
    __syncthreads();
    if (t == 0) ak[e] = red[0] + red[1] + red[2] + red[3];
  } else {
    const int d0 = (bid - 64) * 64;
    #pragma unroll
    for (int p = 0; p < 4; ++p) {
      const int e  = p * 16 + (t >> 4);
      const int dd = (t & 15) * 4;
      const float4 k4 = *(const float4*)(keys + (size_t)e * D_N + d0 + dd);
      tl[dd + 0][e] = (__bf16)k4.x; tl[dd + 1][e] = (__bf16)k4.y;
      tl[dd + 2][e] = (__bf16)k4.z; tl[dd + 3][e] = (__bf16)k4.w;
    }
    __syncthreads();
    #pragma unroll
    for (int p = 0; p < 2; ++p) {
      const int dd = p * 32 + (t >> 3);
      const int l8 = t & 7;
      const bf16x8 v = *(const bf16x8*)&tl[dd][l8 * 8];
      *(bf16x8*)(kT + (size_t)(d0 + dd) * E_N + l8 * 8) = v;
    }
  }
}

__global__ __launch_bounds__(256) void main_kernel(
    const float* __restrict__ z, const float* __restrict__ sinv,
    const float* __restrict__ ak, const __bf16* __restrict__ sk,
    const __bf16* __restrict__ kT,
    float* __restrict__ out_sim, float* __restrict__ out_we)
{
  constexpr int ZS = D_N + 8;            // bf16 elems; 16B-aligned rows, bank offset 4/row
  __shared__ __bf16 zlds[ROWS * ZS];     // 33 KB
  __shared__ float azs[ROWS];
  __shared__ float simb[ROWS][68];       // +4 pad
  __shared__ __bf16 wlds[ROWS][72];      // +8 pad

  const int t  = threadIdx.x;
  const int b0 = blockIdx.x * ROWS;
  const int wave = t >> 6;
  const int lane = t & 63;
  const int ln = lane & 15;
  const int q  = lane >> 4;

  // ---------- stage z (phase A: d 0..512) ; Az partial ----------
  const int sr = t >> 4;                 // row 0..15 (16 threads per row)
  const int sc = t & 15;
  const float* zrow = z + (size_t)(b0 + sr) * D_N;
  float az = 0.f;
  #pragma unroll
  for (int l = 0; l < 8; ++l) {
    const int c = sc * 4 + l * 64;
    const float4 z4 = *(const float4*)(zrow + c);
    const float4 s4 = *(const float4*)(sinv + c);
    az += s4.x * z4.x * z4.x + s4.y * z4.y * z4.y + s4.z * z4.z * z4.z + s4.w * z4.w * z4.w;
    bf16x4 zb;
    zb[0] = (__bf16)z4.x; zb[1] = (__bf16)z4.y; zb[2] = (__bf16)z4.z; zb[3] = (__bf16)z4.w;
    *(bf16x4*)(&zlds[sr * ZS + c]) = zb;
  }
  const float akv = ak[wave * 16 + ln];
  __syncthreads();                       // phase-A zlds ready

  // ---------- GEMM1 half 1 (K 0..512) overlapped with z phase B (d 512..1024) ----------
  f32x4 acc = {0.f, 0.f, 0.f, 0.f};
  const __bf16* bp = sk + (size_t)(wave * 16 + ln) * D_N + q * 8;
  const __bf16* ap = &zlds[ln * ZS + q * 8];
  {
    // issue phase-B global loads first so their vmcnt overlaps the MFMAs
    float4 z4b[4], s4b[4];
    #pragma unroll
    for (int l = 0; l < 4; ++l) {
      const int c = 512 + sc * 4 + l * 64;
      z4b[l] = *(const float4*)(zrow + c);
      s4b[l] = *(const float4*)(sinv + c);
    }
    #pragma unroll
    for (int ks = 0; ks < 16; ++ks) {
      const bf16x8 bfr = *(const bf16x8*)(bp + ks * 32);
      const bf16x8 afr = *(const bf16x8*)(ap + ks * 32);
      acc = __builtin_amdgcn_mfma_f32_16x16x32_bf16(afr, bfr, acc, 0, 0, 0);
    }
    #pragma unroll
    for (int l = 0; l < 4; ++l) {
      const int c = 512 + sc * 4 + l * 64;
      const float4 z4 = z4b[l], s4 = s4b[l];
      az += s4.x * z4.x * z4.x + s4.y * z4.y * z4.y + s4.z * z4.z * z4.z + s4.w * z4.w * z4.w;
      bf16x4 zb;
      zb[0] = (__bf16)z4.x; zb[1] = (__bf16)z4.y; zb[2] = (__bf16)z4.z; zb[3] = (__bf16)z4.w;
      *(bf16x4*)(&zlds[sr * ZS + c]) = zb;
    }
    #pragma unroll
    for (int l = 0; l < 4; ++l) {
      const int c = 768 + sc * 4 + l * 64;
      const float4 z4 = *(const float4*)(zrow + c);
      const float4 s4 = *(const float4*)(sinv + c);
      az += s4.x * z4.x * z4.x + s4.y * z4.y * z4.y + s4.z * z4.z * z4.z + s4.w * z4.w * z4.w;
      bf16x4 zb;
      zb[0] = (__bf16)z4.x; zb[1] = (__bf16)z4.y; zb[2] = (__bf16)z4.z; zb[3] = (__bf16)z4.w;
      *(bf16x4*)(&zlds[sr * ZS + c]) = zb;
    }
  }
  az += __shfl_xor(az, 1); az += __shfl_xor(az, 2);
  az += __shfl_xor(az, 4); az += __shfl_xor(az, 8);
  if (sc == 0) azs[sr] = az;
  __syncthreads();                       // phase-B zlds + azs ready

  // ---------- GEMM1 half 2 (K 512..1024) ----------
  #pragma unroll
  for (int ks = 16; ks < 32; ++ks) {
    const bf16x8 bfr = *(const bf16x8*)(bp + ks * 32);
    const bf16x8 afr = *(const bf16x8*)(ap + ks * 32);
    acc = __builtin_amdgcn_mfma_f32_16x16x32_bf16(afr, bfr, acc, 0, 0, 0);
  }
  #pragma unroll
  for (int i = 0; i < 4; ++i) {
    const int row = q * 4 + i;           // C: row = quad*4+reg, col = lane&15
    const float dist = azs[row] + akv - 2.0f * acc[i];
    simb[row][wave * 16 + ln] = 1.0f / (1.0f + dist);
  }
  // prefetch GEMM2's first kT A-frags (pure global, overlaps softmax)
  const __bf16* kp0 = kT + (size_t)(wave * 256 + ln) * E_N + q * 8;
  const bf16x8 pa0 = *(const bf16x8*)(kp0);
  const bf16x8 pa1 = *(const bf16x8*)(kp0 + 32);
  __syncthreads();                       // simb ready

  // ---------- softmax over e — all 16 quads, one row each ----------
  {
    const int row = wave * 4 + q;        // quad owns a row; 16 lanes x 4 e each
    const f32x4 v4 = *(const f32x4*)&simb[row][ln * 4];
    float mx = fmaxf(fmaxf(v4[0], v4[1]), fmaxf(v4[2], v4[3]));
    mx = fmaxf(mx, __shfl_xor(mx, 1)); mx = fmaxf(mx, __shfl_xor(mx, 2));
    mx = fmaxf(mx, __shfl_xor(mx, 4)); mx = fmaxf(mx, __shfl_xor(mx, 8));
    float e0 = __expf(v4[0] - mx), e1 = __expf(v4[1] - mx);
    float e2 = __expf(v4[2] - mx), e3 = __expf(v4[3] - mx);
    float sum = e0 + e1 + e2 + e3;
    sum += __shfl_xor(sum, 1); sum += __shfl_xor(sum, 2);
    sum += __shfl_xor(sum, 4); sum += __shfl_xor(sum, 8);
    const float inv = 1.0f / sum;
    bf16x4 wv;
    wv[0] = (__bf16)(e0 * inv); wv[1] = (__bf16)(e1 * inv);
    wv[2] = (__bf16)(e2 * inv); wv[3] = (__bf16)(e3 * inv);
    *(bf16x4*)&wlds[row][ln * 4] = wv;
  }
  __syncthreads();                       // wlds ready

  // ---------- similarity -> global (coalesced float4) ----------
  {
    const float4 sv = *(const float4*)&simb[t >> 4][(t & 15) * 4];
    *(float4*)(out_sim + (size_t)(b0 + (t >> 4)) * E_N + (t & 15) * 4) = sv;
  }

  // ---------- GEMM2 (operands swapped): D[m=d][n=brow] -> f32x4 stores ----------
  // A = kT rows (m=d), B = w rows (n=brow); lane stores out[b0+ln][d0+q*4 .. +3]
  const bf16x8 wb0 = *(const bf16x8*)&wlds[ln][q * 8];       // B: n=ln, k=e 0..31
  const bf16x8 wb1 = *(const bf16x8*)&wlds[ln][32 + q * 8];  //           k=e 32..63
  float* orow = out_we + (size_t)(b0 + ln) * D_N + wave * 256 + q * 4;
  #pragma unroll
  for (int i = 0; i < 16; ++i) {
    const int d0 = wave * 256 + i * 16;  // wave owns contiguous 256-d slab
    bf16x8 a0f, a1f;
    if (i == 0) { a0f = pa0; a1f = pa1; }
    else {
      const __bf16* kp = kT + (size_t)(d0 + ln) * E_N + q * 8;
      a0f = *(const bf16x8*)(kp);
      a1f = *(const bf16x8*)(kp + 32);
    }
    f32x4 o = {0.f, 0.f, 0.f, 0.f};
    o = __builtin_amdgcn_mfma_f32_16x16x32_bf16(a0f, wb0, o, 0, 0, 0);
    o = __builtin_amdgcn_mfma_f32_16x16x32_bf16(a1f, wb1, o, 0, 0, 0);
    *(f32x4*)(orow + i * 16) = o;
  }
}

extern "C" void kernel_launch(void* const* d_in, const int* in_sizes, int n_in,
                              void* d_out, int out_size, void* d_ws, size_t ws_size,
                              hipStream_t stream)
{
  const float* z    = (const float*)d_in[0];
  const float* keys = (const float*)d_in[1];
  const float* ls   = (const float*)d_in[2];
  float* out_sim = (float*)d_out;
  float* out_we  = out_sim + (size_t)B_N * E_N;
  char* ws = (char*)d_ws;
  float*  sinv = (float*)(ws);
  float*  ak   = (float*)(ws + 4096);
  __bf16* sk   = (__bf16*)(ws + 4352);
  __bf16* kT   = (__bf16*)(ws + 135424);
  prep_kernel<<<80, 256, 0, stream>>>(keys, ls, sinv, ak, sk, kT);
  main_kernel<<<B_N / ROWS, 256, 0, stream>>>(z, sinv, ak, sk, kT, out_sim, out_we);
}

// Round 6
// 84.321 us; speedup vs baseline: 1.0292x; 1.0292x over previous
//
#include <hip/hip_runtime.h>
#include <hip/hip_bf16.h>

#define B_N 4096
#define E_N 64
#define D_N 1024
#define ROWS 16

typedef __bf16 bf16x8 __attribute__((ext_vector_type(8)));
typedef __bf16 bf16x4 __attribute__((ext_vector_type(4)));
typedef float f32x4 __attribute__((ext_vector_type(4)));

// ws layout (bytes):
// [0, 4096)        sinv   (1024 f32)
// [4096, 4352)     Ak     (64 f32)
// [4352, 135424)   sk_bf16 [64][1024]   (sigma_inv * keys, K-major)
// [135424, 266496) kT_bf16 [1024][64]   (raw keys transposed, K(=e)-major)

__global__ __launch_bounds__(256) void prep_kernel(
    const float* __restrict__ keys, const float* __restrict__ lsig,
    float* __restrict__ sinv, float* __restrict__ ak,
    __bf16* __restrict__ sk, __bf16* __restrict__ kT)
{
  __shared__ float red[4];
  __shared__ __bf16 tl[64][72];          // transpose tile, +8 pad
  const int bid = blockIdx.x;
  const int t = threadIdx.x;

  if (bid < 64) {
    const int e = bid;
    const float4 k4 = *(const float4*)(keys + e * D_N + 4 * t);
    const float4 l4 = *(const float4*)(lsig + 4 * t);
    float4 s4;
    s4.x = expf(-l4.x); s4.y = expf(-l4.y); s4.z = expf(-l4.z); s4.w = expf(-l4.w);
    if (e == 0) *(float4*)(sinv + 4 * t) = s4;
    const float4 sk4 = make_float4(s4.x * k4.x, s4.y * k4.y, s4.z * k4.z, s4.w * k4.w);
    bf16x4 skb;
    skb[0] = (__bf16)sk4.x; skb[1] = (__bf16)sk4.y; skb[2] = (__bf16)sk4.z; skb[3] = (__bf16)sk4.w;
    *(bf16x4*)(sk + e * D_N + 4 * t) = skb;
    float p = sk4.x * k4.x + sk4.y * k4.y + sk4.z * k4.z + sk4.w * k4.w;
    #pragma unroll
    for (int off = 32; off > 0; off >>= 1) p += __shfl_down(p, off);
    if ((t & 63) == 0) red[t >> 6] = p;
    __syncthreads();
    if (t == 0) ak[e] = red[0] + red[1] + red[2] + red[3];
  } else {
    const int d0 = (bid - 64) * 64;
    #pragma unroll
    for (int p = 0; p < 4; ++p) {
      const int e  = p * 16 + (t >> 4);
      const int dd = (t & 15) * 4;
      const float4 k4 = *(const float4*)(keys + (size_t)e * D_N + d0 + dd);
      tl[dd + 0][e] = (__bf16)k4.x; tl[dd + 1][e] = (__bf16)k4.y;
      tl[dd + 2][e] = (__bf16)k4.z; tl[dd + 3][e] = (__bf16)k4.w;
    }
    __syncthreads();
    #pragma unroll
    for (int p = 0; p < 2; ++p) {
      const int dd = p * 32 + (t >> 3);
      const int l8 = t & 7;
      const bf16x8 v = *(const bf16x8*)&tl[dd][l8 * 8];
      *(bf16x8*)(kT + (size_t)(d0 + dd) * E_N + l8 * 8) = v;
    }
  }
}

__global__ __launch_bounds__(256) void main_kernel(
    const float* __restrict__ z, const float* __restrict__ sinv,
    const float* __restrict__ ak, const __bf16* __restrict__ sk,
    const __bf16* __restrict__ kT,
    float* __restrict__ out_sim, float* __restrict__ out_we)
{
  constexpr int ZS = D_N + 8;            // bf16 elems; 16B-aligned rows, breaks bank pattern
  __shared__ __bf16 zlds[ROWS * ZS];     // 33 KB
  __shared__ float azs[ROWS];
  __shared__ float simb[ROWS][68];       // +4 pad
  __shared__ __bf16 wlds[ROWS][72];      // +8 pad

  const int t  = threadIdx.x;
  const int b0 = blockIdx.x * ROWS;
  const int wave = t >> 6;
  const int lane = t & 63;
  const int ln = lane & 15;
  const int q  = lane >> 4;

  // ---------- stage z -> bf16 LDS (nontemporal: z read exactly once) ----------
  const int sr = t >> 4;                 // row 0..15 (16 threads per row)
  const int sc = t & 15;
  const float* zrow = z + (size_t)(b0 + sr) * D_N;
  float az = 0.f;
  #pragma unroll
  for (int l = 0; l < 16; ++l) {
    const int c = sc * 4 + l * 64;
    const f32x4 z4 = __builtin_nontemporal_load((const f32x4*)(zrow + c));
    const f32x4 s4 = *(const f32x4*)(sinv + c);
    az += s4[0] * z4[0] * z4[0] + s4[1] * z4[1] * z4[1]
        + s4[2] * z4[2] * z4[2] + s4[3] * z4[3] * z4[3];
    bf16x4 zb;
    zb[0] = (__bf16)z4[0]; zb[1] = (__bf16)z4[1];
    zb[2] = (__bf16)z4[2]; zb[3] = (__bf16)z4[3];
    *(bf16x4*)(&zlds[sr * ZS + c]) = zb;
  }
  az += __shfl_xor(az, 1); az += __shfl_xor(az, 2);
  az += __shfl_xor(az, 4); az += __shfl_xor(az, 8);
  if (sc == 0) azs[sr] = az;
  const float akv = ak[wave * 16 + ln];
  __syncthreads();                       // zlds + azs ready

  // ---------- GEMM1: G[16 rows][64 experts], one 16-expert tile per wave ----------
  f32x4 acc = {0.f, 0.f, 0.f, 0.f};
  const __bf16* bp = sk + (size_t)(wave * 16 + ln) * D_N + q * 8;
  const __bf16* ap = &zlds[ln * ZS + q * 8];
  #pragma unroll 8
  for (int ks = 0; ks < 32; ++ks) {
    const bf16x8 bfr = *(const bf16x8*)(bp + ks * 32);
    const bf16x8 afr = *(const bf16x8*)(ap + ks * 32);
    acc = __builtin_amdgcn_mfma_f32_16x16x32_bf16(afr, bfr, acc, 0, 0, 0);
  }
  #pragma unroll
  for (int i = 0; i < 4; ++i) {
    const int row = q * 4 + i;           // C: row = quad*4+reg, col = lane&15
    const float dist = azs[row] + akv - 2.0f * acc[i];
    simb[row][wave * 16 + ln] = 1.0f / (1.0f + dist);
  }
  // prefetch GEMM2's first kT A-frags (pure global, overlaps softmax)
  const __bf16* kp0 = kT + (size_t)(wave * 256 + ln) * E_N + q * 8;
  const bf16x8 pa0 = *(const bf16x8*)(kp0);
  const bf16x8 pa1 = *(const bf16x8*)(kp0 + 32);
  __syncthreads();                       // simb ready

  // ---------- softmax over e — all 16 quads, one row each ----------
  {
    const int row = wave * 4 + q;        // quad owns a row; 16 lanes x 4 e each
    const f32x4 v4 = *(const f32x4*)&simb[row][ln * 4];
    float mx = fmaxf(fmaxf(v4[0], v4[1]), fmaxf(v4[2], v4[3]));
    mx = fmaxf(mx, __shfl_xor(mx, 1)); mx = fmaxf(mx, __shfl_xor(mx, 2));
    mx = fmaxf(mx, __shfl_xor(mx, 4)); mx = fmaxf(mx, __shfl_xor(mx, 8));
    float e0 = __expf(v4[0] - mx), e1 = __expf(v4[1] - mx);
    float e2 = __expf(v4[2] - mx), e3 = __expf(v4[3] - mx);
    float sum = e0 + e1 + e2 + e3;
    sum += __shfl_xor(sum, 1); sum += __shfl_xor(sum, 2);
    sum += __shfl_xor(sum, 4); sum += __shfl_xor(sum, 8);
    const float inv = 1.0f / sum;
    bf16x4 wv;
    wv[0] = (__bf16)(e0 * inv); wv[1] = (__bf16)(e1 * inv);
    wv[2] = (__bf16)(e2 * inv); wv[3] = (__bf16)(e3 * inv);
    *(bf16x4*)&wlds[row][ln * 4] = wv;
  }
  __syncthreads();                       // wlds ready

  // ---------- similarity -> global (coalesced, nontemporal) ----------
  {
    const f32x4 sv = *(const f32x4*)&simb[t >> 4][(t & 15) * 4];
    __builtin_nontemporal_store(sv,
        (f32x4*)(out_sim + (size_t)(b0 + (t >> 4)) * E_N + (t & 15) * 4));
  }

  // ---------- GEMM2 (operands swapped): D[m=d][n=brow] -> f32x4 nt stores ----------
  // A = kT rows (m=d), B = w rows (n=brow); lane stores out[b0+ln][d0+q*4 .. +3]
  const bf16x8 wb0 = *(const bf16x8*)&wlds[ln][q * 8];       // B: n=ln, k=e 0..31
  const bf16x8 wb1 = *(const bf16x8*)&wlds[ln][32 + q * 8];  //           k=e 32..63
  float* orow = out_we + (size_t)(b0 + ln) * D_N + wave * 256 + q * 4;
  #pragma unroll
  for (int i = 0; i < 16; ++i) {
    const int d0 = wave * 256 + i * 16;  // wave owns contiguous 256-d slab
    bf16x8 a0f, a1f;
    if (i == 0) { a0f = pa0; a1f = pa1; }
    else {
      const __bf16* kp = kT + (size_t)(d0 + ln) * E_N + q * 8;
      a0f = *(const bf16x8*)(kp);
      a1f = *(const bf16x8*)(kp + 32);
    }
    f32x4 o = {0.f, 0.f, 0.f, 0.f};
    o = __builtin_amdgcn_mfma_f32_16x16x32_bf16(a0f, wb0, o, 0, 0, 0);
    o = __builtin_amdgcn_mfma_f32_16x16x32_bf16(a1f, wb1, o, 0, 0, 0);
    __builtin_nontemporal_store(o, (f32x4*)(orow + i * 16));
  }
}

extern "C" void kernel_launch(void* const* d_in, const int* in_sizes, int n_in,
                              void* d_out, int out_size, void* d_ws, size_t ws_size,
                              hipStream_t stream)
{
  const float* z    = (const float*)d_in[0];
  const float* keys = (const float*)d_in[1];
  const float* ls   = (const float*)d_in[2];
  float* out_sim = (float*)d_out;
  float* out_we  = out_sim + (size_t)B_N * E_N;
  char* ws = (char*)d_ws;
  float*  sinv = (float*)(ws);
  float*  ak   = (float*)(ws + 4096);
  __bf16* sk   = (__bf16*)(ws + 4352);
  __bf16* kT   = (__bf16*)(ws + 135424);
  prep_kernel<<<80, 256, 0, stream>>>(keys, ls, sinv, ak, sk, kT);
  main_kernel<<<B_N / ROWS, 256, 0, stream>>>(z, sinv, ak, sk, kT, out_sim, out_we);
}